// Round 10
// baseline (2215.692 us; speedup 1.0000x reference)
//
#include <hip/hip_runtime.h>
#include <hip/hip_fp16.h>

typedef _Float16 f16;
typedef _Float16 f16x2 __attribute__((ext_vector_type(2)));
typedef _Float16 f16x8 __attribute__((ext_vector_type(8)));
typedef float    f32x4 __attribute__((ext_vector_type(4)));
typedef unsigned int u32;
typedef unsigned long long u64;

#define BN_EPS 1e-5f

static constexpr int BB  = 32;    // batch
static constexpr int CC  = 128;   // channels
static constexpr int HWN = 1024;  // H*W = L
static constexpr int RIN = 256;
static constexpr int RH  = 512;
static constexpr int OCN = 128;

// ---------------------------------------------------------------- BN stats
__global__ void bn_stats_kernel(const float* __restrict__ x,
                                const float* __restrict__ gamma,
                                const float* __restrict__ beta,
                                float* __restrict__ scale,
                                float* __restrict__ shift) {
    int c = blockIdx.x;
    int tid = threadIdx.x;
    float s = 0.f, s2 = 0.f;
    const float* xc = x + (size_t)c * HWN;
    for (int idx = tid; idx < BB * HWN; idx += 256) {
        int b = idx >> 10, hw = idx & 1023;
        float v = xc[(size_t)b * (CC * HWN) + hw];
        s += v; s2 += v * v;
    }
    for (int off = 32; off > 0; off >>= 1) {
        s  += __shfl_down(s, off, 64);
        s2 += __shfl_down(s2, off, 64);
    }
    __shared__ float ls[4], ls2[4];
    int wv = tid >> 6, ln = tid & 63;
    if (ln == 0) { ls[wv] = s; ls2[wv] = s2; }
    __syncthreads();
    if (tid == 0) {
        float ts  = ls[0] + ls[1] + ls[2] + ls[3];
        float ts2 = ls2[0] + ls2[1] + ls2[2] + ls2[3];
        const float inv_n = 1.0f / (BB * HWN);
        float mean = ts * inv_n;
        float var  = ts2 * inv_n - mean * mean;
        float rstd = rsqrtf(var + BN_EPS);
        float sc = gamma[c] * rstd;
        scale[c] = sc;
        shift[c] = beta[c] - mean * sc;
    }
}

// ------------------------------------------- normalize + transpose -> A1 f16
__global__ void prep_x_kernel(const float* __restrict__ x,
                              const float* __restrict__ scale,
                              const float* __restrict__ shift,
                              f16* __restrict__ A1) {
    __shared__ float tile[32][33];
    int tx = threadIdx.x, ty = threadIdx.y;  // 32 x 8
    int hb = blockIdx.x, cb = blockIdx.y, b = blockIdx.z;
    #pragma unroll
    for (int k = 0; k < 4; k++) {
        int c  = cb * 32 + ty + 8 * k;
        int hw = hb * 32 + tx;
        tile[ty + 8 * k][tx] = x[(size_t)b * (CC * HWN) + (size_t)c * HWN + hw];
    }
    __syncthreads();
    #pragma unroll
    for (int k = 0; k < 4; k++) {
        int hw = hb * 32 + ty + 8 * k;
        int c  = cb * 32 + tx;
        float v = tile[tx][ty + 8 * k];
        A1[(size_t)(b * HWN + hw) * CC + c] = (f16)(v * scale[c] + shift[c]);
    }
}

// ------------------------------------------------------------ weight prep
__global__ void prep_w_kernel(const float* __restrict__ w_in,
                              const float* __restrict__ w_ih,
                              const float* __restrict__ w_out,
                              const float* __restrict__ w_hh,
                              const float* __restrict__ b_ih,
                              const float* __restrict__ b_hh,
                              f16* __restrict__ w_in_h,
                              f16* __restrict__ w_ih_h,
                              f16* __restrict__ w_out_h,
                              u32* __restrict__ wr,
                              float* __restrict__ bihh,
                              u64* __restrict__ comm,
                              u32* __restrict__ rz) {
    int idx = blockIdx.x * 256 + threadIdx.x;
    if (idx < 32768) { w_in_h[idx] = (f16)w_in[idx]; return; }
    idx -= 32768;
    if (idx < 131072) { w_ih_h[idx] = (f16)w_ih[idx]; return; }
    idx -= 131072;
    if (idx < 65536) { w_out_h[idx] = (f16)w_out[idx]; return; }
    idx -= 65536;
    if (idx < 131072) {
        int s = idx >> 15, rem = idx & 32767;
        int t = rem >> 6, k = rem & 63;
        int r = k >> 4, n = k & 15;
        int jg = t & 31, sl = t >> 5;
        int j  = s * 128 + 4 * jg + r;       // output row
        int i2 = sl * 16 + n;                // h-pair index
        f16 lo = (f16)w_hh[(size_t)j * 512 + 2 * i2];
        f16 hi = (f16)w_hh[(size_t)j * 512 + 2 * i2 + 1];
        wr[idx] = (u32)__builtin_bit_cast(unsigned short, lo) |
                  ((u32)__builtin_bit_cast(unsigned short, hi) << 16);
        return;
    }
    idx -= 131072;
    if (idx < 512) { bihh[idx] = b_ih[idx] + b_hh[idx]; return; }
    idx -= 512;
    if (idx < 32768) { comm[idx] = 0ULL; return; }  // slow + fast buffers
    idx -= 32768;
    if (idx < 16) rz[idx] = 0u;                     // rendezvous state
}

// ------------------------------------------------------------- MFMA GEMM
template <int MODE>
__global__ void gemm_kernel(const f16* __restrict__ A,
                            const f16* __restrict__ W,
                            const float* __restrict__ bias,
                            void* __restrict__ outp,
                            int N, int K) {
    int wave = threadIdx.x >> 6;
    int lane = threadIdx.x & 63;
    int q = lane >> 4, r = lane & 15;
    int bm = blockIdx.x * 256 + wave * 64;
    int bn = blockIdx.y * 64;

    f32x4 acc[4][4];
    #pragma unroll
    for (int i = 0; i < 4; i++)
        #pragma unroll
        for (int j = 0; j < 4; j++)
            acc[i][j] = (f32x4){0.f, 0.f, 0.f, 0.f};

    const f16* Ap = A + (size_t)(bm + r) * K + 8 * q;
    const f16* Wp = W + (size_t)(bn + r) * K + 8 * q;

    for (int k = 0; k < K; k += 32) {
        f16x8 av[4], bv[4];
        #pragma unroll
        for (int i = 0; i < 4; i++)
            av[i] = *(const f16x8*)(Ap + (size_t)(16 * i) * K + k);
        #pragma unroll
        for (int i = 0; i < 4; i++)
            bv[i] = *(const f16x8*)(Wp + (size_t)(16 * i) * K + k);
        #pragma unroll
        for (int mi = 0; mi < 4; mi++)
            #pragma unroll
            for (int ni = 0; ni < 4; ni++)
                acc[mi][ni] = __builtin_amdgcn_mfma_f32_16x16x32_f16(
                    av[mi], bv[ni], acc[mi][ni], 0, 0, 0);
    }

    #pragma unroll
    for (int mi = 0; mi < 4; mi++) {
        #pragma unroll
        for (int ni = 0; ni < 4; ni++) {
            int col = bn + 16 * ni + r;
            float bval = bias[col];
            #pragma unroll
            for (int i = 0; i < 4; i++) {
                int row = bm + 16 * mi + 4 * q + i;
                float val = acc[mi][ni][i] + bval;
                if (MODE == 0) {
                    val = val - tanhf(val);
                    ((f16*)outp)[(size_t)row * N + col] = (f16)val;
                } else if (MODE == 1) {
                    ((f16*)outp)[(size_t)row * N + col] = (f16)val;
                } else {
                    int b = row >> 10, hw = row & 1023;
                    ((float*)outp)[(size_t)b * (OCN * HWN) + (size_t)col * HWN + hw] = val;
                }
            }
        }
    }
}

// ---------------------------------------------------------------- RNN scan
// XCC_ID RENDEZVOUS (this round's change): r9 showed the wg%8 same-XCD
// assumption is unverified and the fast path is structurally dead for
// cross-XCD pairs (poller L2 caches a stale line forever). Now: 256 WGs
// (1/CU, enforced by 81KB LDS), each reads HW_REG_XCC_ID and claims
// rank=atomicAdd(cnt[xcd]); ranks 0-15 take the 16 slice-tasks of batches
// 4*xcd..4*xcd+3 -> all 4 slices of a batch PROVABLY on one XCD. Rank>=16
// WGs wait for all 256 arrivals, adopt orphans (skew safety) or exit.
// Publishers always dual-publish (fast local-L2 + slow MALL) -> any skew
// degrades to r7 latency, never wrongness (G16). Primary pollers: sc0 loads
// at ~250cyc cadence, slow check only every 8th try.
__device__ __forceinline__ float dot2acc(u32 w, f16x2 h, float c) {
#if __has_builtin(__builtin_amdgcn_fdot2)
    return __builtin_amdgcn_fdot2(__builtin_bit_cast(f16x2, w), h, c, false);
#else
    f16x2 a = __builtin_bit_cast(f16x2, w);
    return c + (float)a[0] * (float)h[0] + (float)a[1] * (float)h[1];
#endif
}

#define ROW16(acc, WA, WB, WC, WD)                                  \
    acc = dot2acc(WA.x, H0,  acc); acc = dot2acc(WA.y, H1,  acc);   \
    acc = dot2acc(WA.z, H2,  acc); acc = dot2acc(WA.w, H3,  acc);   \
    acc = dot2acc(WB.x, H4,  acc); acc = dot2acc(WB.y, H5,  acc);   \
    acc = dot2acc(WB.z, H6,  acc); acc = dot2acc(WB.w, H7,  acc);   \
    acc = dot2acc(WC.x, H8,  acc); acc = dot2acc(WC.y, H9,  acc);   \
    acc = dot2acc(WC.z, H10, acc); acc = dot2acc(WC.w, H11, acc);   \
    acc = dot2acc(WD.x, H12, acc); acc = dot2acc(WD.y, H13, acc);   \
    acc = dot2acc(WD.z, H14, acc); acc = dot2acc(WD.w, H15, acc)

__global__ __launch_bounds__(512, 2) void rnn_kernel(const u32* WR,
                                                     f16* __restrict__ xh,
                                                     u64* slow, u64* fast,
                                                     u32* rz) {
    const int t = threadIdx.x;

    __shared__ __align__(16) f16 hbuf[512];
    __shared__ float part[16][128];
    __shared__ u32 task_sh;
    __shared__ u32 lds_pad[18432];   // occupancy fence: forces 1 block/CU

    // ---- rendezvous: claim a (batch, slice) task on THIS XCD
    if (t == 0) {
        u32 xcd;
        asm volatile("s_getreg_b32 %0, hwreg(HW_REG_XCC_ID)" : "=s"(xcd));
        xcd &= 7u;
        u32 rank = __hip_atomic_fetch_add(&rz[1 + xcd], 1u,
                                          __ATOMIC_RELAXED, __HIP_MEMORY_SCOPE_AGENT);
        __hip_atomic_fetch_add(&rz[0], 1u,
                               __ATOMIC_RELEASE, __HIP_MEMORY_SCOPE_AGENT);
        u32 tk;
        if (rank < 16u) {
            tk = 0x8000u | (xcd * 16u + rank);   // primary: same-XCD batch group
        } else {
            u32 orank = __hip_atomic_fetch_add(&rz[9], 1u,
                                               __ATOMIC_RELAXED, __HIP_MEMORY_SCOPE_AGENT);
            u32 g = 0;
            while (__hip_atomic_load(&rz[0], __ATOMIC_ACQUIRE,
                                     __HIP_MEMORY_SCOPE_AGENT) < 256u &&
                   ++g < (1u << 27)) {}
            tk = 0xFFFFFFFFu;
            u32 acc = 0;
            for (int x = 0; x < 8; x++) {
                u32 c = __hip_atomic_load(&rz[1 + x], __ATOMIC_RELAXED,
                                          __HIP_MEMORY_SCOPE_AGENT);
                if (c > 16u) c = 16u;
                u32 d = 16u - c;
                if (orank < acc + d) {
                    u32 r2 = c + (orank - acc);
                    tk = (u32)x * 16u + r2;      // orphan: cross-XCD, slow path
                    break;
                }
                acc += d;
            }
        }
        task_sh = tk;
    }
    if (t < 256) ((u32*)hbuf)[t] = 0u;
    __syncthreads();
    const u32 task = task_sh;
    if (task == 0xFFFFFFFFu) return;             // spare WG, no orphan work
    if (task == 0x7FFFFFFFu) lds_pad[t] = t;     // never true; defeats DCE
    const int primary = (task >> 15) & 1;
    const int b = (task & 127) >> 2;             // batch
    const int s = task & 3;                      // slice: rows [128s,128s+128)
    const int jg = t & 31;
    const int sl = t >> 5;

    // weight words -> 16 named uint4 (provenance hidden; non-restrict
    // pointers so in-loop stores may alias -> no remat into the loop).
    unsigned long long wpa =
        (unsigned long long)(WR + ((size_t)(s * 512 + t) << 6));
    asm volatile("" : "+v"(wpa));
    const uint4* wp = (const uint4*)wpa;
    uint4 W0 = wp[0],  W1 = wp[1],  W2 = wp[2],  W3 = wp[3];
    uint4 W4 = wp[4],  W5 = wp[5],  W6 = wp[6],  W7 = wp[7];
    uint4 W8 = wp[8],  W9 = wp[9],  W10 = wp[10], W11 = wp[11];
    uint4 W12 = wp[12], W13 = wp[13], W14 = wp[14], W15 = wp[15];

    f16* xb = xh + (size_t)b * (HWN * RH) + s * 128;  // + step*RH + t
    float xnext = 0.f;
    if (t < 128) xnext = (float)xb[t];

    u64* cbS = slow + (size_t)b * 256;
    u64* cbF = fast + (size_t)b * 256;
    const uint4* hq = (const uint4*)hbuf;

    for (int step = 0; step < HWN; step++) {
        float xcur = xnext;
        if (t < 128 && step + 1 < HWN)
            xnext = (float)xb[(size_t)(step + 1) * RH + t];

        // ---- partial y for 4 rows over this thread's 16 h-pairs
        uint4 q0 = hq[sl*4+0], q1 = hq[sl*4+1], q2 = hq[sl*4+2], q3 = hq[sl*4+3];
        f16x2 H0  = __builtin_bit_cast(f16x2, q0.x), H1  = __builtin_bit_cast(f16x2, q0.y);
        f16x2 H2  = __builtin_bit_cast(f16x2, q0.z), H3  = __builtin_bit_cast(f16x2, q0.w);
        f16x2 H4  = __builtin_bit_cast(f16x2, q1.x), H5  = __builtin_bit_cast(f16x2, q1.y);
        f16x2 H6  = __builtin_bit_cast(f16x2, q1.z), H7  = __builtin_bit_cast(f16x2, q1.w);
        f16x2 H8  = __builtin_bit_cast(f16x2, q2.x), H9  = __builtin_bit_cast(f16x2, q2.y);
        f16x2 H10 = __builtin_bit_cast(f16x2, q2.z), H11 = __builtin_bit_cast(f16x2, q2.w);
        f16x2 H12 = __builtin_bit_cast(f16x2, q3.x), H13 = __builtin_bit_cast(f16x2, q3.y);
        f16x2 H14 = __builtin_bit_cast(f16x2, q3.z), H15 = __builtin_bit_cast(f16x2, q3.w);
        float a0 = 0.f, a1 = 0.f, a2 = 0.f, a3 = 0.f;
        ROW16(a0, W0,  W1,  W2,  W3);
        ROW16(a1, W4,  W5,  W6,  W7);
        ROW16(a2, W8,  W9,  W10, W11);
        ROW16(a3, W12, W13, W14, W15);
        *(f32x4*)&part[sl][4 * jg] = (f32x4){a0, a1, a2, a3};
        __syncthreads();

        const u32 tag = (u32)(step + 1);
        const size_t pbase = (size_t)(tag & 1) * 8192;

        // ---- waves 4-6: poll for the 3 partner slices
        if (t >= 256 && t < 448) {
            int pi = (t - 256) >> 6;
            int widx = t & 63;
            int p = pi + (pi >= s ? 1 : 0);
            const u64* aF = &cbF[pbase + p * 64 + widx];
            u64* aS = &cbS[pbase + p * 64 + widx];
            u64 v;
            u32 g = 0;
            if (primary) {
                for (;;) {
                    // same-XCD L2 read (bypass own L1 via sc0), read-only
                    asm volatile("global_load_dwordx2 %0, %1, off sc0\n\t"
                                 "s_waitcnt vmcnt(0)"
                                 : "=&v"(v) : "v"(aF) : "memory");
                    if ((u32)(v >> 32) == tag) break;
                    ++g;
                    if ((g & 7u) == 7u) {   // occasional MALL safety check
                        v = __hip_atomic_load(aS, __ATOMIC_RELAXED,
                                              __HIP_MEMORY_SCOPE_AGENT);
                        if ((u32)(v >> 32) == tag) break;
                    }
                    if (g > (1u << 17)) break;
                }
            } else {
                for (;;) {
                    v = __hip_atomic_load(aS, __ATOMIC_RELAXED,
                                          __HIP_MEMORY_SCOPE_AGENT);
                    if ((u32)(v >> 32) == tag) break;
                    if (++g > (1u << 17)) break;
                }
            }
            ((u32*)hbuf)[p * 64 + widx] = (u32)v;
        }
        // ---- waves 0-1: finalize own 128 rows, publish ASAP
        if (t < 128) {
            float y = xcur;
            #pragma unroll
            for (int k = 0; k < 16; k++) y += part[k][t];
            float h = tanhf(y);
            f16 hf = (f16)h;
            u32 hu = (u32)__builtin_bit_cast(unsigned short, hf);
            u32 other = (u32)__shfl_down((int)hu, 1, 64);
            if ((t & 1) == 0) {
                u64 v = ((u64)tag << 32) | (u64)(hu | (other << 16));
                // fast: plain write-through -> lands in local XCD L2
                __hip_atomic_store(&cbF[pbase + s * 64 + (t >> 1)], v,
                                   __ATOMIC_RELAXED, __HIP_MEMORY_SCOPE_WORKGROUP);
                // slow: MALL mirror for cross-XCD correctness
                __hip_atomic_store(&cbS[pbase + s * 64 + (t >> 1)], v,
                                   __ATOMIC_RELAXED, __HIP_MEMORY_SCOPE_AGENT);
            }
            hbuf[s * 128 + t] = hf;                 // own slice into local h
            xb[(size_t)step * RH + t] = hf;         // hs output (in place)
        }
        __syncthreads();
    }
}

// ------------------------------------------------------------------ launch
extern "C" void kernel_launch(void* const* d_in, const int* in_sizes, int n_in,
                              void* d_out, int out_size, void* d_ws, size_t ws_size,
                              hipStream_t stream) {
    const float* x     = (const float*)d_in[0];
    const float* gamma = (const float*)d_in[1];
    const float* beta  = (const float*)d_in[2];
    const float* w_in  = (const float*)d_in[3];
    const float* b_in  = (const float*)d_in[4];
    const float* w_ih  = (const float*)d_in[5];
    const float* b_ih  = (const float*)d_in[6];
    const float* w_hh  = (const float*)d_in[7];
    const float* b_hh  = (const float*)d_in[8];
    const float* w_out = (const float*)d_in[9];
    const float* b_out = (const float*)d_in[10];

    char* ws = (char*)d_ws;
    float* scale   = (float*)(ws + 0);         //   512 B
    float* shift   = (float*)(ws + 512);       //   512 B
    float* bihh    = (float*)(ws + 1024);      //  2 KB
    f16*   w_in_h  = (f16*)(ws + 4096);        // 64 KB
    f16*   w_ih_h  = (f16*)(ws + 69632);       // 256 KB
    f16*   w_out_h = (f16*)(ws + 331776);      // 128 KB
    u32*   wr      = (u32*)(ws + 462848);      // 512 KB packed W_hh
    u64*   cslow   = (u64*)(ws + 987136);      // 128 KB slow comm (MALL)
    u64*   cfast   = (u64*)(ws + 1118208);     // 128 KB fast comm (local L2)
    u32*   rz      = (u32*)(ws + 1249280);     // 64 B rendezvous state
    f16*   xh      = (f16*)(ws + 1310720);     // 32 MB xgate, overwritten by hs
    f16*   A1      = (f16*)(ws + 34865152);    //  8 MB
    f16*   inp     = (f16*)(ws + 43253760);    // 16 MB (ends 60030976)

    bn_stats_kernel<<<128, 256, 0, stream>>>(x, gamma, beta, scale, shift);
    prep_w_kernel<<<1539, 256, 0, stream>>>(w_in, w_ih, w_out, w_hh, b_ih, b_hh,
                                            w_in_h, w_ih_h, w_out_h, wr, bihh,
                                            cslow, rz);
    prep_x_kernel<<<dim3(32, 4, 32), dim3(32, 8), 0, stream>>>(x, scale, shift, A1);
    gemm_kernel<0><<<dim3(128, 4), 256, 0, stream>>>(A1, w_in_h, b_in, (void*)inp, RIN, CC);
    gemm_kernel<1><<<dim3(128, 8), 256, 0, stream>>>(inp, w_ih_h, bihh, (void*)xh, RH, RIN);
    rnn_kernel<<<256, 512, 0, stream>>>(wr, xh, cslow, cfast, rz);
    gemm_kernel<2><<<dim3(128, 2), 256, 0, stream>>>(xh, w_out_h, b_out, d_out, OCN, RH);
}

// Round 12
// 1640.169 us; speedup vs baseline: 1.3509x; 1.3509x over previous
//
#include <hip/hip_runtime.h>
#include <hip/hip_fp16.h>

typedef _Float16 f16;
typedef _Float16 f16x2 __attribute__((ext_vector_type(2)));
typedef _Float16 f16x8 __attribute__((ext_vector_type(8)));
typedef float    f32x4 __attribute__((ext_vector_type(4)));
typedef unsigned int u32;
typedef unsigned long long u64;

#define BN_EPS 1e-5f

static constexpr int BB  = 32;    // batch
static constexpr int CC  = 128;   // channels
static constexpr int HWN = 1024;  // H*W = L
static constexpr int RIN = 256;
static constexpr int RH  = 512;
static constexpr int OCN = 128;

// ---------------------------------------------------------------- BN stats
__global__ void bn_stats_kernel(const float* __restrict__ x,
                                const float* __restrict__ gamma,
                                const float* __restrict__ beta,
                                float* __restrict__ scale,
                                float* __restrict__ shift) {
    int c = blockIdx.x;
    int tid = threadIdx.x;
    float s = 0.f, s2 = 0.f;
    const float* xc = x + (size_t)c * HWN;
    for (int idx = tid; idx < BB * HWN; idx += 256) {
        int b = idx >> 10, hw = idx & 1023;
        float v = xc[(size_t)b * (CC * HWN) + hw];
        s += v; s2 += v * v;
    }
    for (int off = 32; off > 0; off >>= 1) {
        s  += __shfl_down(s, off, 64);
        s2 += __shfl_down(s2, off, 64);
    }
    __shared__ float ls[4], ls2[4];
    int wv = tid >> 6, ln = tid & 63;
    if (ln == 0) { ls[wv] = s; ls2[wv] = s2; }
    __syncthreads();
    if (tid == 0) {
        float ts  = ls[0] + ls[1] + ls[2] + ls[3];
        float ts2 = ls2[0] + ls2[1] + ls2[2] + ls2[3];
        const float inv_n = 1.0f / (BB * HWN);
        float mean = ts * inv_n;
        float var  = ts2 * inv_n - mean * mean;
        float rstd = rsqrtf(var + BN_EPS);
        float sc = gamma[c] * rstd;
        scale[c] = sc;
        shift[c] = beta[c] - mean * sc;
    }
}

// ------------------------------------------- normalize + transpose -> A1 f16
__global__ void prep_x_kernel(const float* __restrict__ x,
                              const float* __restrict__ scale,
                              const float* __restrict__ shift,
                              f16* __restrict__ A1) {
    __shared__ float tile[32][33];
    int tx = threadIdx.x, ty = threadIdx.y;  // 32 x 8
    int hb = blockIdx.x, cb = blockIdx.y, b = blockIdx.z;
    #pragma unroll
    for (int k = 0; k < 4; k++) {
        int c  = cb * 32 + ty + 8 * k;
        int hw = hb * 32 + tx;
        tile[ty + 8 * k][tx] = x[(size_t)b * (CC * HWN) + (size_t)c * HWN + hw];
    }
    __syncthreads();
    #pragma unroll
    for (int k = 0; k < 4; k++) {
        int hw = hb * 32 + ty + 8 * k;
        int c  = cb * 32 + tx;
        float v = tile[tx][ty + 8 * k];
        A1[(size_t)(b * HWN + hw) * CC + c] = (f16)(v * scale[c] + shift[c]);
    }
}

// ------------------------------------------------------------ weight prep
// round-7 packing: word idx -> (slice s, thread t, reg k); reg k = r*16+n
__global__ void prep_w_kernel(const float* __restrict__ w_in,
                              const float* __restrict__ w_ih,
                              const float* __restrict__ w_out,
                              const float* __restrict__ w_hh,
                              const float* __restrict__ b_ih,
                              const float* __restrict__ b_hh,
                              f16* __restrict__ w_in_h,
                              f16* __restrict__ w_ih_h,
                              f16* __restrict__ w_out_h,
                              u32* __restrict__ wr,
                              float* __restrict__ bihh,
                              u64* __restrict__ comm) {
    int idx = blockIdx.x * 256 + threadIdx.x;
    if (idx < 32768) { w_in_h[idx] = (f16)w_in[idx]; return; }
    idx -= 32768;
    if (idx < 131072) { w_ih_h[idx] = (f16)w_ih[idx]; return; }
    idx -= 131072;
    if (idx < 65536) { w_out_h[idx] = (f16)w_out[idx]; return; }
    idx -= 65536;
    if (idx < 131072) {
        int s = idx >> 15, rem = idx & 32767;
        int t = rem >> 6, k = rem & 63;
        int r = k >> 4, n = k & 15;
        int jg = t & 31, sl = t >> 5;
        int j  = s * 128 + 4 * jg + r;       // output row
        int i2 = sl * 16 + n;                // h-pair index
        f16 lo = (f16)w_hh[(size_t)j * 512 + 2 * i2];
        f16 hi = (f16)w_hh[(size_t)j * 512 + 2 * i2 + 1];
        wr[idx] = (u32)__builtin_bit_cast(unsigned short, lo) |
                  ((u32)__builtin_bit_cast(unsigned short, hi) << 16);
        return;
    }
    idx -= 131072;
    if (idx < 512) { bihh[idx] = b_ih[idx] + b_hh[idx]; return; }
    idx -= 512;
    if (idx < 16384) comm[idx] = 0ULL;
}

// ------------------------------------------------------------- MFMA GEMM
template <int MODE>
__global__ void gemm_kernel(const f16* __restrict__ A,
                            const f16* __restrict__ W,
                            const float* __restrict__ bias,
                            void* __restrict__ outp,
                            int N, int K) {
    int wave = threadIdx.x >> 6;
    int lane = threadIdx.x & 63;
    int q = lane >> 4, r = lane & 15;
    int bm = blockIdx.x * 256 + wave * 64;
    int bn = blockIdx.y * 64;

    f32x4 acc[4][4];
    #pragma unroll
    for (int i = 0; i < 4; i++)
        #pragma unroll
        for (int j = 0; j < 4; j++)
            acc[i][j] = (f32x4){0.f, 0.f, 0.f, 0.f};

    const f16* Ap = A + (size_t)(bm + r) * K + 8 * q;
    const f16* Wp = W + (size_t)(bn + r) * K + 8 * q;

    for (int k = 0; k < K; k += 32) {
        f16x8 av[4], bv[4];
        #pragma unroll
        for (int i = 0; i < 4; i++)
            av[i] = *(const f16x8*)(Ap + (size_t)(16 * i) * K + k);
        #pragma unroll
        for (int i = 0; i < 4; i++)
            bv[i] = *(const f16x8*)(Wp + (size_t)(16 * i) * K + k);
        #pragma unroll
        for (int mi = 0; mi < 4; mi++)
            #pragma unroll
            for (int ni = 0; ni < 4; ni++)
                acc[mi][ni] = __builtin_amdgcn_mfma_f32_16x16x32_f16(
                    av[mi], bv[ni], acc[mi][ni], 0, 0, 0);
    }

    #pragma unroll
    for (int mi = 0; mi < 4; mi++) {
        #pragma unroll
        for (int ni = 0; ni < 4; ni++) {
            int col = bn + 16 * ni + r;
            float bval = bias[col];
            #pragma unroll
            for (int i = 0; i < 4; i++) {
                int row = bm + 16 * mi + 4 * q + i;
                float val = acc[mi][ni][i] + bval;
                if (MODE == 0) {
                    val = val - tanhf(val);
                    ((f16*)outp)[(size_t)row * N + col] = (f16)val;
                } else if (MODE == 1) {
                    ((f16*)outp)[(size_t)row * N + col] = (f16)val;
                } else {
                    int b = row >> 10, hw = row & 1023;
                    ((float*)outp)[(size_t)b * (OCN * HWN) + (size_t)col * HWN + hw] = val;
                }
            }
        }
    }
}

// ---------------------------------------------------------------- RNN scan
// Round-7 structure (128 WGs, 1407us baseline) + register pin, take 2.
// r11's `"+v"(uint4)` failed: backend can't tie 128-bit indirect operands.
// Fix: unpack to 64 named u32 SCALARS (free renaming) and pin with four
// asm volatile blocks of 16 scalar "+v" each at loop top. Each iteration
// "redefines" the weight VGPRs -> memory copy stale after iter 0 ->
// reload/remat ILLEGAL -> first guaranteed register residency of the
// session (VGPR_Count was 52 in r3,r4,r5,r7,r9,r10 = silent L2 streaming).
// Comm: r7's relaxed agent-scope u64 atomics (payload+tag, parity dbuf);
// pollers waves 4-6, finalize waves 0-1.
__device__ __forceinline__ float dot2acc(u32 w, f16x2 h, float c) {
#if __has_builtin(__builtin_amdgcn_fdot2)
    return __builtin_amdgcn_fdot2(__builtin_bit_cast(f16x2, w), h, c, false);
#else
    f16x2 a = __builtin_bit_cast(f16x2, w);
    return c + (float)a[0] * (float)h[0] + (float)a[1] * (float)h[1];
#endif
}

#define DOT16(acc, A0,A1,A2,A3,A4,A5,A6,A7,A8,A9,Aa,Ab,Ac,Ad,Ae,Af)  \
    acc = dot2acc(A0, H0,  acc); acc = dot2acc(A1, H1,  acc);        \
    acc = dot2acc(A2, H2,  acc); acc = dot2acc(A3, H3,  acc);        \
    acc = dot2acc(A4, H4,  acc); acc = dot2acc(A5, H5,  acc);        \
    acc = dot2acc(A6, H6,  acc); acc = dot2acc(A7, H7,  acc);        \
    acc = dot2acc(A8, H8,  acc); acc = dot2acc(A9, H9,  acc);        \
    acc = dot2acc(Aa, H10, acc); acc = dot2acc(Ab, H11, acc);        \
    acc = dot2acc(Ac, H12, acc); acc = dot2acc(Ad, H13, acc);        \
    acc = dot2acc(Ae, H14, acc); acc = dot2acc(Af, H15, acc);

__global__ __launch_bounds__(512, 2) void rnn_kernel(const u32* __restrict__ WR,
                                                     f16* __restrict__ xh,
                                                     u64* __restrict__ comm) {
    const int wg = blockIdx.x;
    const int b  = wg & 31;   // batch
    const int s  = wg >> 5;   // slice: rows [128s, 128s+128)
    const int t  = threadIdx.x;
    const int jg = t & 31;    // 4 rows: 128s + 4jg .. +3
    const int sl = t >> 5;    // 16 h-pair slices of 16 pairs

    __shared__ __align__(16) f16 hbuf[512];
    __shared__ float part[16][128];

    // one-time clean vector loads, unpacked to 64 named u32 scalars
    const uint4* wp = (const uint4*)(WR + ((size_t)(s * 512 + t) << 6));
    uint4 q0_ = wp[0],  q1_ = wp[1],  q2_ = wp[2],  q3_ = wp[3];
    uint4 q4_ = wp[4],  q5_ = wp[5],  q6_ = wp[6],  q7_ = wp[7];
    uint4 q8_ = wp[8],  q9_ = wp[9],  qa_ = wp[10], qb_ = wp[11];
    uint4 qc_ = wp[12], qd_ = wp[13], qe_ = wp[14], qf_ = wp[15];
    u32 w00 = q0_.x, w01 = q0_.y, w02 = q0_.z, w03 = q0_.w;
    u32 w04 = q1_.x, w05 = q1_.y, w06 = q1_.z, w07 = q1_.w;
    u32 w08 = q2_.x, w09 = q2_.y, w10 = q2_.z, w11 = q2_.w;
    u32 w12 = q3_.x, w13 = q3_.y, w14 = q3_.z, w15 = q3_.w;
    u32 w16 = q4_.x, w17 = q4_.y, w18 = q4_.z, w19 = q4_.w;
    u32 w20 = q5_.x, w21 = q5_.y, w22 = q5_.z, w23 = q5_.w;
    u32 w24 = q6_.x, w25 = q6_.y, w26 = q6_.z, w27 = q6_.w;
    u32 w28 = q7_.x, w29 = q7_.y, w30 = q7_.z, w31 = q7_.w;
    u32 w32 = q8_.x, w33 = q8_.y, w34 = q8_.z, w35 = q8_.w;
    u32 w36 = q9_.x, w37 = q9_.y, w38 = q9_.z, w39 = q9_.w;
    u32 w40 = qa_.x, w41 = qa_.y, w42 = qa_.z, w43 = qa_.w;
    u32 w44 = qb_.x, w45 = qb_.y, w46 = qb_.z, w47 = qb_.w;
    u32 w48 = qc_.x, w49 = qc_.y, w50 = qc_.z, w51 = qc_.w;
    u32 w52 = qd_.x, w53 = qd_.y, w54 = qd_.z, w55 = qd_.w;
    u32 w56 = qe_.x, w57 = qe_.y, w58 = qe_.z, w59 = qe_.w;
    u32 w60 = qf_.x, w61 = qf_.y, w62 = qf_.z, w63 = qf_.w;

    if (t < 256) ((u32*)hbuf)[t] = 0u;
    __syncthreads();

    f16* xb = xh + (size_t)b * (HWN * RH) + s * 128;  // + step*RH + t
    float xnext = 0.f;
    if (t < 128) xnext = (float)xb[t];

    u64* cb = comm + (size_t)b * 256;  // [parity]*8192 + b*256 + slice*64 + word
    const uint4* hq = (const uint4*)hbuf;

    for (int step = 0; step < HWN; step++) {
        // REGISTER PIN (scalar "+v" — backend-supported): each iteration
        // "redefines" the 64 weight VGPRs; reload from memory is illegal.
        asm volatile("" : "+v"(w00), "+v"(w01), "+v"(w02), "+v"(w03),
                          "+v"(w04), "+v"(w05), "+v"(w06), "+v"(w07),
                          "+v"(w08), "+v"(w09), "+v"(w10), "+v"(w11),
                          "+v"(w12), "+v"(w13), "+v"(w14), "+v"(w15));
        asm volatile("" : "+v"(w16), "+v"(w17), "+v"(w18), "+v"(w19),
                          "+v"(w20), "+v"(w21), "+v"(w22), "+v"(w23),
                          "+v"(w24), "+v"(w25), "+v"(w26), "+v"(w27),
                          "+v"(w28), "+v"(w29), "+v"(w30), "+v"(w31));
        asm volatile("" : "+v"(w32), "+v"(w33), "+v"(w34), "+v"(w35),
                          "+v"(w36), "+v"(w37), "+v"(w38), "+v"(w39),
                          "+v"(w40), "+v"(w41), "+v"(w42), "+v"(w43),
                          "+v"(w44), "+v"(w45), "+v"(w46), "+v"(w47));
        asm volatile("" : "+v"(w48), "+v"(w49), "+v"(w50), "+v"(w51),
                          "+v"(w52), "+v"(w53), "+v"(w54), "+v"(w55),
                          "+v"(w56), "+v"(w57), "+v"(w58), "+v"(w59),
                          "+v"(w60), "+v"(w61), "+v"(w62), "+v"(w63));

        float xcur = xnext;
        if (t < 128 && step + 1 < HWN)
            xnext = (float)xb[(size_t)(step + 1) * RH + t];

        // ---- partial y for 4 rows over this thread's 16 h-pairs
        uint4 h0 = hq[sl*4+0], h1 = hq[sl*4+1], h2 = hq[sl*4+2], h3 = hq[sl*4+3];
        f16x2 H0  = __builtin_bit_cast(f16x2, h0.x), H1  = __builtin_bit_cast(f16x2, h0.y);
        f16x2 H2  = __builtin_bit_cast(f16x2, h0.z), H3  = __builtin_bit_cast(f16x2, h0.w);
        f16x2 H4  = __builtin_bit_cast(f16x2, h1.x), H5  = __builtin_bit_cast(f16x2, h1.y);
        f16x2 H6  = __builtin_bit_cast(f16x2, h1.z), H7  = __builtin_bit_cast(f16x2, h1.w);
        f16x2 H8  = __builtin_bit_cast(f16x2, h2.x), H9  = __builtin_bit_cast(f16x2, h2.y);
        f16x2 H10 = __builtin_bit_cast(f16x2, h2.z), H11 = __builtin_bit_cast(f16x2, h2.w);
        f16x2 H12 = __builtin_bit_cast(f16x2, h3.x), H13 = __builtin_bit_cast(f16x2, h3.y);
        f16x2 H14 = __builtin_bit_cast(f16x2, h3.z), H15 = __builtin_bit_cast(f16x2, h3.w);
        float a0 = 0.f, a1 = 0.f, a2 = 0.f, a3 = 0.f;
        DOT16(a0, w00,w01,w02,w03,w04,w05,w06,w07,w08,w09,w10,w11,w12,w13,w14,w15)
        DOT16(a1, w16,w17,w18,w19,w20,w21,w22,w23,w24,w25,w26,w27,w28,w29,w30,w31)
        DOT16(a2, w32,w33,w34,w35,w36,w37,w38,w39,w40,w41,w42,w43,w44,w45,w46,w47)
        DOT16(a3, w48,w49,w50,w51,w52,w53,w54,w55,w56,w57,w58,w59,w60,w61,w62,w63)
        *(f32x4*)&part[sl][4 * jg] = (f32x4){a0, a1, a2, a3};
        __syncthreads();

        const u32 tag = (u32)(step + 1);
        const size_t pbase = (size_t)(tag & 1) * 8192;

        // ---- waves 4-6: poll for the 3 partner slices
        if (t >= 256 && t < 448) {
            int pi = (t - 256) >> 6;
            int widx = t & 63;
            int p = pi + (pi >= s ? 1 : 0);
            u64* addr = &cb[pbase + p * 64 + widx];
            u64 v;
            int guard = 0;
            do {
                v = __hip_atomic_load(addr, __ATOMIC_RELAXED,
                                      __HIP_MEMORY_SCOPE_AGENT);
            } while ((u32)(v >> 32) != tag && ++guard < (1 << 17));
            ((u32*)hbuf)[p * 64 + widx] = (u32)v;
        }
        // ---- waves 0-1: finalize own 128 rows, publish ASAP
        if (t < 128) {
            float y = xcur;
            #pragma unroll
            for (int k = 0; k < 16; k++) y += part[k][t];
            float h = tanhf(y);
            f16 hf = (f16)h;
            u32 hu = (u32)__builtin_bit_cast(unsigned short, hf);
            u32 other = (u32)__shfl_down((int)hu, 1, 64);
            if ((t & 1) == 0) {
                u64 v = ((u64)tag << 32) | (u64)(hu | (other << 16));
                __hip_atomic_store(&cb[pbase + s * 64 + (t >> 1)], v,
                                   __ATOMIC_RELAXED, __HIP_MEMORY_SCOPE_AGENT);
            }
            hbuf[s * 128 + t] = hf;                 // own slice into local h
            xb[(size_t)step * RH + t] = hf;         // hs output (in place)
        }
        __syncthreads();
    }
}

// ------------------------------------------------------------------ launch
extern "C" void kernel_launch(void* const* d_in, const int* in_sizes, int n_in,
                              void* d_out, int out_size, void* d_ws, size_t ws_size,
                              hipStream_t stream) {
    const float* x     = (const float*)d_in[0];
    const float* gamma = (const float*)d_in[1];
    const float* beta  = (const float*)d_in[2];
    const float* w_in  = (const float*)d_in[3];
    const float* b_in  = (const float*)d_in[4];
    const float* w_ih  = (const float*)d_in[5];
    const float* b_ih  = (const float*)d_in[6];
    const float* w_hh  = (const float*)d_in[7];
    const float* b_hh  = (const float*)d_in[8];
    const float* w_out = (const float*)d_in[9];
    const float* b_out = (const float*)d_in[10];

    char* ws = (char*)d_ws;
    float* scale   = (float*)(ws + 0);         //   512 B
    float* shift   = (float*)(ws + 512);       //   512 B
    float* bihh    = (float*)(ws + 1024);      //  2 KB
    f16*   w_in_h  = (f16*)(ws + 4096);        // 64 KB
    f16*   w_ih_h  = (f16*)(ws + 69632);       // 256 KB
    f16*   w_out_h = (f16*)(ws + 331776);      // 128 KB
    u32*   wr      = (u32*)(ws + 462848);      // 512 KB packed W_hh
    u64*   comm    = (u64*)(ws + 987136);      // 128 KB h-exchange
    f16*   xh      = (f16*)(ws + 1179648);     // 32 MB xgate, overwritten by hs
    f16*   A1      = (f16*)(ws + 34734080);    //  8 MB
    f16*   inp     = (f16*)(ws + 43122688);    // 16 MB (ends 59899904)

    bn_stats_kernel<<<128, 256, 0, stream>>>(x, gamma, beta, scale, shift);
    prep_w_kernel<<<1474, 256, 0, stream>>>(w_in, w_ih, w_out, w_hh, b_ih, b_hh,
                                            w_in_h, w_ih_h, w_out_h, wr, bihh, comm);
    prep_x_kernel<<<dim3(32, 4, 32), dim3(32, 8), 0, stream>>>(x, scale, shift, A1);
    gemm_kernel<0><<<dim3(128, 4), 256, 0, stream>>>(A1, w_in_h, b_in, (void*)inp, RIN, CC);
    gemm_kernel<1><<<dim3(128, 8), 256, 0, stream>>>(inp, w_ih_h, bihh, (void*)xh, RH, RIN);
    rnn_kernel<<<128, 512, 0, stream>>>(wr, xh, comm);
    gemm_kernel<2><<<dim3(128, 2), 256, 0, stream>>>(xh, w_out_h, b_out, d_out, OCN, RH);
}